// Round 7
// baseline (392.707 us; speedup 1.0000x reference)
//
#include <hip/hip_runtime.h>

#define NN 50000
#define NE 400000
#define NBLK 196   // ceil(NN/256)

using short8 = __attribute__((ext_vector_type(8))) short;
using f32x4  = __attribute__((ext_vector_type(4))) float;
using u16x2  = __attribute__((ext_vector_type(2))) unsigned short;
using u16x4  = __attribute__((ext_vector_type(4))) unsigned short;

__device__ __forceinline__ unsigned short f2b(float f) {
    union { float f; unsigned int u; } x; x.f = f;
    unsigned int u = x.u;
    u += 0x7fffu + ((u >> 16) & 1u);   // RNE
    return (unsigned short)(u >> 16);
}
__device__ __forceinline__ float b2f(unsigned short u) {
    union { unsigned int u; float f; } x; x.u = ((unsigned int)u) << 16;
    return x.f;
}

#define SWZ(b, row) ((b) ^ (((row) & 7) << 4))

// async global->LDS, 16B per lane; LDS dest must be wave-uniform-base + lane*16
__device__ __forceinline__ void gload16(const void* g, void* l) {
    __builtin_amdgcn_global_load_lds(
        (const __attribute__((address_space(1))) void*)g,
        (__attribute__((address_space(3))) void*)l, 16, 0, 0);
}

// ---------------- CSR build ----------------
__global__ __launch_bounds__(256) void zero2_k(int* a, int* b) {
    int i = blockIdx.x * 256 + threadIdx.x;
    if (i < NN) { a[i] = 0; b[i] = 0; }
}
__global__ __launch_bounds__(256) void count_k(const int* __restrict__ dst, int* __restrict__ indeg) {
    int e = blockIdx.x * 256 + threadIdx.x;
    if (e < NE) atomicAdd(&indeg[dst[e]], 1);
}
__global__ __launch_bounds__(256) void scan1_k(const int* __restrict__ indeg, int* __restrict__ tmp,
                                               int* __restrict__ bsum) {
    __shared__ int s[256];
    int t = threadIdx.x, i = blockIdx.x * 256 + t;
    int v = (i < NN) ? indeg[i] : 0;
    s[t] = v; __syncthreads();
    for (int off = 1; off < 256; off <<= 1) {
        int x = (t >= off) ? s[t - off] : 0;
        __syncthreads();
        s[t] += x;
        __syncthreads();
    }
    if (i < NN) tmp[i] = s[t];
    if (t == 255) bsum[blockIdx.x] = s[255];
}
__global__ __launch_bounds__(256) void scan2_k(const int* __restrict__ bsum, int* __restrict__ boff) {
    __shared__ int s[256];
    int t = threadIdx.x;
    int v = (t < NBLK) ? bsum[t] : 0;
    s[t] = v; __syncthreads();
    for (int off = 1; off < 256; off <<= 1) {
        int x = (t >= off) ? s[t - off] : 0;
        __syncthreads();
        s[t] += x;
        __syncthreads();
    }
    if (t < NBLK) boff[t] = s[t] - v;   // exclusive
}
__global__ __launch_bounds__(256) void scan3_k(const int* __restrict__ tmp, const int* __restrict__ indeg,
                                               const int* __restrict__ boff, int* __restrict__ rowptr,
                                               float* __restrict__ dinv) {
    int i = blockIdx.x * 256 + threadIdx.x;
    if (i < NN) {
        rowptr[i] = tmp[i] - indeg[i] + boff[i >> 8];
        dinv[i] = rsqrtf((float)(1 + indeg[i]));
    }
    if (i == 0) rowptr[NN] = NE;
}
__global__ __launch_bounds__(256) void fill_k(const int* __restrict__ src, const int* __restrict__ dst,
                                              const float* __restrict__ dinv, const int* __restrict__ rowptr,
                                              int* __restrict__ cursor, int2* __restrict__ ebn) {
    int e = blockIdx.x * 256 + threadIdx.x;
    if (e >= NE) return;
    int s = src[e], d = dst[e];
    int pos = atomicAdd(&cursor[d], 1);
    ebn[rowptr[d] + pos] = make_int2(s, __float_as_int(dinv[s] * dinv[d]));
}

// ---------------- x fp32 -> bf16 (streaming, BW-bound) ----------------
__global__ __launch_bounds__(256) void xcast_k(const float* __restrict__ x, unsigned short* __restrict__ xb) {
    long i = (long)blockIdx.x * 256 + threadIdx.x;   // 8 elems per thread
    const long total = (long)NN * 512 / 8;
    if (i >= total) return;
    float4 f0 = *(const float4*)(x + i * 8);
    float4 f1 = *(const float4*)(x + i * 8 + 4);
    short8 v;
    v[0] = (short)f2b(f0.x); v[1] = (short)f2b(f0.y);
    v[2] = (short)f2b(f0.z); v[3] = (short)f2b(f0.w);
    v[4] = (short)f2b(f1.x); v[5] = (short)f2b(f1.y);
    v[6] = (short)f2b(f1.z); v[7] = (short)f2b(f1.w);
    *(short8*)(xb + i * 8) = v;
}

// ---------------- merged weight cast+transpose (9 segments, one launch) ----------------
struct WSegs {
    const float* W[9];
    unsigned short* Wt[9];
    int K[9], N[9], Kp[9];
    int c0[10];
};
__global__ __launch_bounds__(256) void wcast_all_k(WSegs s) {
    int blk = blockIdx.x;
    #pragma unroll
    for (int g = 0; g < 9; g++) {
        if (blk >= s.c0[g] && blk < s.c0[g + 1]) {
            int idx = (blk - s.c0[g]) * 256 + threadIdx.x;
            int Kp = s.Kp[g];
            int n = idx / Kp, k = idx % Kp;
            float v = (n < s.N[g] && k < s.K[g]) ? s.W[g][(size_t)k * s.N[g] + n] : 0.0f;
            s.Wt[g][idx] = f2b(v);
        }
    }
}

// ---------------- MFMA bf16 GEMM: global_load_lds staging, dbuf LDS, 1 barrier/K-step --
// C[M x ldc](bf16) = A[M x lda](bf16) @ Wt[ldc x Kp]^T (+bias). 4 waves (2x2).
// LDS dest is LINEAR (o*16); global source is pre-swizzled so SWZ-reads see logical layout.
template<int BM, int BN>
__global__ __launch_bounds__(256) void gemm_mfma_k(
    const unsigned short* __restrict__ A, const unsigned short* __restrict__ Bt,
    const float* __restrict__ bias, unsigned short* __restrict__ C,
    int M, int lda, int Kp, int N, int ldc) {
    constexpr int MR = BM / 32;
    constexpr int NF = BN / 32;
    constexpr int nA = BM / 32;      // 16B chunks per thread for A tile
    constexpr int nB = BN / 32;
    constexpr int BUFB = (BM + BN) * 128;
    __shared__ __align__(16) char lds[2 * BUFB];

    int tid = threadIdx.x;
    int lane = tid & 63, wave = tid >> 6;
    int wr = wave >> 1, wc = wave & 1;
    int lr = lane & 15, lk = lane >> 4;
    int r0 = blockIdx.x * BM, c0 = blockIdx.y * BN;

    f32x4 acc[MR][NF];
    #pragma unroll
    for (int m = 0; m < MR; m++)
        #pragma unroll
        for (int n = 0; n < NF; n++)
            acc[m][n] = (f32x4){0.f, 0.f, 0.f, 0.f};

    auto ISSUE = [&](int k0, char* buf) {
        char* AsB = buf;
        char* BsB = buf + BM * 128;
        #pragma unroll
        for (int c = 0; c < nA; c++) {
            int o = tid + c * 256;
            int row = o >> 3;
            int octg = (o & 7) ^ (row & 7);             // inverse swizzle on source
            int gr = min(r0 + row, M - 1);              // clamp: OOB rows read row M-1, discarded at write
            gload16(A + (size_t)gr * lda + k0 + octg * 8, AsB + o * 16);
        }
        #pragma unroll
        for (int c = 0; c < nB; c++) {
            int o = tid + c * 256;
            int row = o >> 3;
            int octg = (o & 7) ^ (row & 7);
            gload16(Bt + (size_t)(c0 + row) * Kp + k0 + octg * 8, BsB + o * 16);
        }
    };

    int nt = Kp >> 6;
    ISSUE(0, lds);
    __syncthreads();                                    // drains vmcnt (tile 0 in LDS)
    for (int t = 0; t < nt; t++) {
        char* cur = lds + (t & 1) * BUFB;
        if (t + 1 < nt) ISSUE((t + 1) << 6, lds + ((t + 1) & 1) * BUFB);  // async into alt buffer
        char* AsB = cur;
        char* BsB = cur + BM * 128;
        #pragma unroll
        for (int kk = 0; kk < 2; kk++) {
            int kb = kk * 64 + lk * 16;
            short8 a[MR], b[NF];
            #pragma unroll
            for (int m = 0; m < MR; m++) {
                int row = wr * (BM / 2) + m * 16 + lr;
                a[m] = *(short8*)(AsB + SWZ(row * 128 + kb, row));
            }
            #pragma unroll
            for (int n = 0; n < NF; n++) {
                int row = wc * (BN / 2) + n * 16 + lr;
                b[n] = *(short8*)(BsB + SWZ(row * 128 + kb, row));
            }
            #pragma unroll
            for (int m = 0; m < MR; m++)
                #pragma unroll
                for (int n = 0; n < NF; n++)
                    acc[m][n] = __builtin_amdgcn_mfma_f32_16x16x32_bf16(a[m], b[n], acc[m][n], 0, 0, 0);
        }
        __syncthreads();    // drains next tile's gload_lds + syncs readers before overwrite
    }

    // epilogue: acc -> LDS (padded) -> coalesced short8 global writes
    constexpr int LDC = BN + 8;
    unsigned short* ldsC = (unsigned short*)lds;
    #pragma unroll
    for (int n = 0; n < NF; n++) {
        int cc = wc * (BN / 2) + n * 16 + lr;
        int gc = c0 + cc;
        float bv = (bias != nullptr && gc < N) ? bias[gc] : 0.0f;
        bool ok = gc < N;
        #pragma unroll
        for (int m = 0; m < MR; m++)
            #pragma unroll
            for (int j = 0; j < 4; j++) {
                int row = wr * (BM / 2) + m * 16 + lk * 4 + j;
                float v = ok ? acc[m][n][j] + bv : 0.0f;
                ldsC[row * LDC + cc] = f2b(v);
            }
    }
    __syncthreads();
    constexpr int CH = (BM * BN) / 2048;
    #pragma unroll
    for (int c = 0; c < CH; c++) {
        int o = tid + c * 256;
        int row = o / (BN / 8), col = (o % (BN / 8)) * 8;
        int gr = r0 + row;
        if (gr < M)
            *(short8*)(C + (size_t)gr * ldc + c0 + col) = *(short8*)(ldsC + row * LDC + col);
    }
}

// ---------------- fused GCN aggregate + combine (CSR gather, bf16) ----------------
template<int VEC> struct BV;
template<> struct BV<1> { using T = unsigned short; };
template<> struct BV<2> { using T = u16x2; };
template<> struct BV<4> { using T = u16x4; };

template<int VEC, bool OUTF32>
__global__ __launch_bounds__(256) void gather_k(
    const unsigned short* __restrict__ h, const unsigned short* __restrict__ base,
    const float* __restrict__ dinv, const float* __restrict__ bias,
    const int2* __restrict__ ebn, const int* __restrict__ rowptr,
    void* __restrict__ outraw, float alpha, int dorelu, int F) {
    const int ld = 64 * VEC;
    int w = (blockIdx.x * 256 + threadIdx.x) >> 6;
    int lane = threadIdx.x & 63;
    if (w >= NN) return;
    using LT = typename BV<VEC>::T;

    float acc[VEC];
    float dn = dinv[w];
    {
        LT t = *(const LT*)(h + (size_t)w * ld + lane * VEC);
        const unsigned short* tu = (const unsigned short*)&t;
        #pragma unroll
        for (int v = 0; v < VEC; v++) acc[v] = b2f(tu[v]) * dn * dn;
    }
    int e = rowptr[w], end = rowptr[w + 1];
    for (; e + 8 <= end; e += 8) {
        int2 q[8];
        #pragma unroll
        for (int i = 0; i < 8; i++) q[i] = ebn[e + i];
        LT t[8];
        #pragma unroll
        for (int i = 0; i < 8; i++) t[i] = *(const LT*)(h + (size_t)q[i].x * ld + lane * VEC);
        #pragma unroll
        for (int i = 0; i < 8; i++) {
            float nr = __int_as_float(q[i].y);
            const unsigned short* u = (const unsigned short*)&t[i];
            #pragma unroll
            for (int v = 0; v < VEC; v++) acc[v] += b2f(u[v]) * nr;
        }
    }
    for (; e + 2 <= end; e += 2) {
        int2 q0 = ebn[e], q1 = ebn[e + 1];
        LT t0 = *(const LT*)(h + (size_t)q0.x * ld + lane * VEC);
        LT t1 = *(const LT*)(h + (size_t)q1.x * ld + lane * VEC);
        float n0 = __int_as_float(q0.y), n1 = __int_as_float(q1.y);
        const unsigned short* u0 = (const unsigned short*)&t0;
        const unsigned short* u1 = (const unsigned short*)&t1;
        #pragma unroll
        for (int v = 0; v < VEC; v++) acc[v] += b2f(u0[v]) * n0 + b2f(u1[v]) * n1;
    }
    if (e < end) {
        int2 q0 = ebn[e];
        LT t0 = *(const LT*)(h + (size_t)q0.x * ld + lane * VEC);
        float n0 = __int_as_float(q0.y);
        const unsigned short* u0 = (const unsigned short*)&t0;
        #pragma unroll
        for (int v = 0; v < VEC; v++) acc[v] += b2f(u0[v]) * n0;
    }
    LT bt = *(const LT*)(base + (size_t)w * ld + lane * VEC);
    const unsigned short* bu = (const unsigned short*)&bt;
    #pragma unroll
    for (int v = 0; v < VEC; v++) {
        int f = lane * VEC + v;
        float a = acc[v] + ((f < F) ? bias[f] : 0.0f);
        if (dorelu) a = fmaxf(a, 0.0f);
        float res = (f < F) ? b2f(bu[v]) + alpha * a : 0.0f;
        if (OUTF32) ((float*)outraw)[(size_t)w * ld + f] = res;
        else        ((unsigned short*)outraw)[(size_t)w * ld + f] = f2b(res);
    }
}

extern "C" void kernel_launch(void* const* d_in, const int* in_sizes, int n_in,
                              void* d_out, int out_size, void* d_ws, size_t ws_size,
                              hipStream_t stream) {
    const float* x   = (const float*)d_in[0];
    const int*   ei  = (const int*)d_in[1];
    const float* W1  = (const float*)d_in[2];  const float* b1  = (const float*)d_in[3];
    const float* W2  = (const float*)d_in[4];  const float* b2  = (const float*)d_in[5];
    const float* W3  = (const float*)d_in[6];  const float* b3  = (const float*)d_in[7];
    const float* Wg1 = (const float*)d_in[8];  const float* bg1 = (const float*)d_in[9];
    const float* Wg2 = (const float*)d_in[10]; const float* bg2 = (const float*)d_in[11];
    const float* Wg3 = (const float*)d_in[12]; const float* bg3 = (const float*)d_in[13];
    const float* Wg4 = (const float*)d_in[14]; const float* bg4 = (const float*)d_in[15];
    const float* Wg5 = (const float*)d_in[16]; const float* bg5 = (const float*)d_in[17];
    const float* Wg6 = (const float*)d_in[18]; const float* bg6 = (const float*)d_in[19];
    const int* srcv = ei;
    const int* dstv = ei + NE;

    float* dinv = (float*)d_ws;                               // 51200 f32
    unsigned short* xb = (unsigned short*)(dinv + 51200);     // NN x 512 bf16
    unsigned short* hA = xb + (size_t)NN * 512;               // NN x 256 bf16
    unsigned short* hB = hA + (size_t)NN * 256;
    unsigned short* hC = hB + (size_t)NN * 256;
    unsigned short* W1t  = hC + (size_t)NN * 256;  // 256x512
    unsigned short* Wg1t = W1t  + 256 * 512;       // 256x256
    unsigned short* W2t  = Wg1t + 256 * 256;       // 64x256
    unsigned short* Wg2t = W2t  + 64 * 256;        // 64x64
    unsigned short* W3t  = Wg2t + 64 * 64;         // 128x64
    unsigned short* Wg3t = W3t  + 128 * 64;        // 128x128
    unsigned short* Wg4t = Wg3t + 128 * 128;
    unsigned short* Wg5t = Wg4t + 128 * 128;
    unsigned short* Wg6t = Wg5t + 128 * 128;
    int* indeg  = (int*)(Wg6t + 128 * 128);
    int* cursor = indeg + 51200;
    int* tmp    = cursor + 51200;
    int* rowptr = tmp + 51200;                     // 51264
    int* bsum   = rowptr + 51264;
    int* boff   = bsum + 256;
    int2* ebn   = (int2*)(boff + 256);             // 400000 x 8B

    // CSR + dinv
    zero2_k<<<NBLK, 256, 0, stream>>>(indeg, cursor);
    count_k<<<(NE + 255) / 256, 256, 0, stream>>>(dstv, indeg);
    scan1_k<<<NBLK, 256, 0, stream>>>(indeg, tmp, bsum);
    scan2_k<<<1, 256, 0, stream>>>(bsum, boff);
    scan3_k<<<NBLK, 256, 0, stream>>>(tmp, indeg, boff, rowptr, dinv);
    fill_k<<<(NE + 255) / 256, 256, 0, stream>>>(srcv, dstv, dinv, rowptr, cursor, ebn);

    // x -> bf16
    xcast_k<<<(int)(((long)NN * 512 / 8 + 255) / 256), 256, 0, stream>>>(x, xb);

    // weights: one merged cast+transpose launch
    {
        WSegs s;
        const float* Ws[9] = {W1, Wg1, W2, Wg2, W3, Wg3, Wg4, Wg5, Wg6};
        unsigned short* Wts[9] = {W1t, Wg1t, W2t, Wg2t, W3t, Wg3t, Wg4t, Wg5t, Wg6t};
        int Ks[9]  = {512, 256, 256, 62, 62, 128, 128, 128, 128};
        int Ns[9]  = {256, 256, 62, 62, 128, 128, 128, 128, 128};
        int Kps[9] = {512, 256, 256, 64, 64, 128, 128, 128, 128};
        int Nps[9] = {256, 256, 64, 64, 128, 128, 128, 128, 128};
        int c = 0;
        for (int g = 0; g < 9; g++) {
            s.W[g] = Ws[g]; s.Wt[g] = Wts[g];
            s.K[g] = Ks[g]; s.N[g] = Ns[g]; s.Kp[g] = Kps[g];
            s.c0[g] = c;
            c += (Kps[g] * Nps[g]) / 256;
        }
        s.c0[9] = c;
        wcast_all_k<<<c, 256, 0, stream>>>(s);
    }

    const int GX = (NN + 63) / 64;          // 782
    const int GG = (NN * 64 + 255) / 256;   // one wave per node

    // L1: x1l -> hA ; h -> hB ; x1 -> hC   (ld 256)
    gemm_mfma_k<64, 128><<<dim3(GX, 2), 256, 0, stream>>>(xb, W1t, b1, hA, NN, 512, 512, 256, 256);
    gemm_mfma_k<64, 128><<<dim3(GX, 2), 256, 0, stream>>>(hA, Wg1t, nullptr, hB, NN, 256, 256, 256, 256);
    gather_k<4, false><<<GG, 256, 0, stream>>>(hB, hA, dinv, bg1, ebn, rowptr, hC, 1.0f, 1, 256);
    // L2: x2l -> hA ; h -> hB ; x2 -> hC   (ld 64)
    gemm_mfma_k<64, 64><<<dim3(GX, 1), 256, 0, stream>>>(hC, W2t, b2, hA, NN, 256, 256, 62, 64);
    gemm_mfma_k<64, 64><<<dim3(GX, 1), 256, 0, stream>>>(hA, Wg2t, nullptr, hB, NN, 64, 64, 62, 64);
    gather_k<1, false><<<GG, 256, 0, stream>>>(hB, hA, dinv, bg2, ebn, rowptr, hC, 1.0f, 1, 62);
    // L3: x3l -> hA ; h -> hB ; x3 -> hC   (ld 128)
    gemm_mfma_k<64, 128><<<dim3(GX, 1), 256, 0, stream>>>(hC, W3t, b3, hA, NN, 64, 64, 128, 128);
    gemm_mfma_k<64, 128><<<dim3(GX, 1), 256, 0, stream>>>(hA, Wg3t, nullptr, hB, NN, 128, 128, 128, 128);
    gather_k<2, false><<<GG, 256, 0, stream>>>(hB, hA, dinv, bg3, ebn, rowptr, hC, 0.5f, 1, 128);
    // L4: h -> hA ; x4 -> hB
    gemm_mfma_k<64, 128><<<dim3(GX, 1), 256, 0, stream>>>(hC, Wg4t, nullptr, hA, NN, 128, 128, 128, 128);
    gather_k<2, false><<<GG, 256, 0, stream>>>(hA, hC, dinv, bg4, ebn, rowptr, hB, 0.5f, 1, 128);
    // L5: h -> hA ; x5 -> hC
    gemm_mfma_k<64, 128><<<dim3(GX, 1), 256, 0, stream>>>(hB, Wg5t, nullptr, hA, NN, 128, 128, 128, 128);
    gather_k<2, false><<<GG, 256, 0, stream>>>(hA, hB, dinv, bg5, ebn, rowptr, hC, 0.25f, 1, 128);
    // L6: h -> hA ; x6 -> d_out (fp32)
    gemm_mfma_k<64, 128><<<dim3(GX, 1), 256, 0, stream>>>(hC, Wg6t, nullptr, hA, NN, 128, 128, 128, 128);
    gather_k<2, true><<<GG, 256, 0, stream>>>(hA, hC, dinv, bg6, ebn, rowptr, d_out, 0.25f, 0, 128);
}